// Round 5
// baseline (166.227 us; speedup 1.0000x reference)
//
#include <hip/hip_runtime.h>
#include <hip/hip_fp8.h>

#define N_IN 1024
#define N_OUT 1024
#define BATCHN 8192

typedef __attribute__((ext_vector_type(4))) int intx4;
typedef __attribute__((ext_vector_type(8))) int intx8;
typedef __attribute__((ext_vector_type(16))) float floatx16;

__device__ __forceinline__ unsigned int f2e4m3(float f) {  // OCP e4m3fn byte
  __hip_fp8_e4m3 v(f);
  return (unsigned int)v.__x;
}
// gelu ~= v * sigmoid(1.702 v) = v * rcp(1 + exp2(-2.4554 v)).
// Max abs err ~0.02 — below the fp8 e4m3 quantization noise of the GEMM path.
__device__ __forceinline__ float gelu_fast(float v) {
  float e = __builtin_amdgcn_exp2f(-2.4554443f * v);
  return v * __builtin_amdgcn_rcpf(1.0f + e);
}

// ---------------------------------------------------------------------------
// Kernel 1: tiny prep.
// blocks [0,1024): W rows -> fp8 e4m3 (x16 scale), written in MFMA-native
//   tiled layout so GEMM B-fragment loads are fully coalesced:
//   for K64-chunk kc and 32-col group g, a 2 KB block holds
//     [sec(0: k bytes lh*32+[0,16), 1: +[16,32))][lane = lh*32 + (col&31)][16B]
//   GEMM reads it as  base + lane*16  (lo)  and  base + 1024 + lane*16  (hi).
// blocks [1024,1088): slopes/intercepts [:,0,:] gather-transpose (s-major).
// ---------------------------------------------------------------------------
__global__ __launch_bounds__(256) void prep_w(const float* __restrict__ W,
                                              unsigned char* __restrict__ Wb8,
                                              const float* __restrict__ slopes,
                                              const float* __restrict__ icpts,
                                              float* __restrict__ slt,
                                              float* __restrict__ ict) {
  const int b = blockIdx.x, t = threadIdx.x;
  if (b < N_OUT) {
    const int o = b;                      // W row == GEMM col
    float4 v = ((const float4*)(W + o * N_IN))[t];  // k bytes 4t..4t+3
    unsigned int pk = f2e4m3(v.x * 16.0f) | (f2e4m3(v.y * 16.0f) << 8) |
                      (f2e4m3(v.z * 16.0f) << 16) | (f2e4m3(v.w * 16.0f) << 24);
    const int kc = t >> 4;                // K64 chunk
    const int lh = (t >> 3) & 1;          // k-half within K64
    const int sec = (t >> 2) & 1;         // lo/hi 16B segment
    const int off = (t & 3) * 4;          // dword within 16B segment
    const int lane = lh * 32 + (o & 31);
    *(unsigned int*)(Wb8 + kc * 65536 + (o >> 5) * 2048 + sec * 1024 +
                     lane * 16 + off) = pk;
  } else {
    const int gb = b - N_OUT;  // 0..63
    const int o = gb * 16 + (t >> 4);
    const int s = t & 15;
    if (s < 9) {
      slt[s * N_OUT + o] = slopes[(long)o * 9216 + s];  // slopes[o][0][s]
      ict[s * N_OUT + o] = icpts[(long)o * 9216 + s];
    }
  }
}

// ---------------------------------------------------------------------------
// Kernel 2: fully fused. 256 blocks x 1024 threads (16 waves), 1 block/CU
// at 4 waves/SIMD (50% occupancy). Block owns 32 rows x all 1024 cols.
//   Phase 1: wave w stages rows 2w..2w+1: gelu(x)*4 -> fp8 in LDS
//            (16B-chunk XOR swizzle) + per-row segment stats into LDS.
//   Phase 2: MX-fp8 GEMM. Wave w computes cols [64w,64w+64): A frags from
//            LDS, B frags direct from L2 in the MFMA-native tiled layout.
//            K-loop start is ROTATED per block (accumulation is order-
//            independent) so the 256 CUs' sweeps of the shared 1 MB Wb8
//            hit different L2 regions instead of convoying on the same
//            lines. No barriers in the K-loop.
//   Phase 3: + bias + rank-18 lin term, full-row LayerNorm via shfl +
//            cross-wave LDS partials, PReLU, nontemporal f32 stores.
// ---------------------------------------------------------------------------
__global__ __launch_bounds__(1024) void fused(const float* __restrict__ x,
                                              const unsigned char* __restrict__ Wb8,
                                              const float* __restrict__ biases,
                                              const float* __restrict__ slt,
                                              const float* __restrict__ ict,
                                              const float* __restrict__ prelu_w,
                                              float* __restrict__ out) {
  __shared__ unsigned char lA[32 * 1024];   // 32 KB fp8 A tile (swizzled)
  __shared__ float seg_lds[32][24];         // sx at [0..8], sc at [12..20]
  __shared__ float2 red[16][32];            // per-wave (sum, sumsq) partials
  __shared__ float2 rowstat[32];            // (mu, rstd)

  const int t = threadIdx.x;
  const int lane = t & 63, w = t >> 6;      // 16 waves
  const int l31 = lane & 31, lh = lane >> 5;
  const int r0 = blockIdx.x * 32;

  // ---- Phase 1: stage A + segment stats (2 rows per wave) --------------
  for (int jr = 0; jr < 2; ++jr) {
    const int rl = 2 * w + jr;  // local row 0..31
    const float* xr = x + (r0 + rl) * N_IN;
    unsigned int* lrow = (unsigned int*)(lA + rl * 1024);
    const int sw = rl & 7;
    float cum[8], cumx[8], totx = 0.f;
#pragma unroll
    for (int s = 0; s < 8; ++s) { cum[s] = 0.f; cumx[s] = 0.f; }
#pragma unroll
    for (int jc = 0; jc < 4; ++jc) {
      float4 v4 = ((const float4*)xr)[lane + 64 * jc];
      float vs[4] = {v4.x, v4.y, v4.z, v4.w};
      unsigned int pk = 0;
#pragma unroll
      for (int e = 0; e < 4; ++e) {
        float v = vs[e];
        pk |= f2e4m3(gelu_fast(v) * 4.0f) << (8 * e);  // x4 scale
        totx += v;
#pragma unroll
        for (int k = 0; k < 8; ++k) {
          bool m = v >= (-1.0f + (float)(k + 1) * (2.0f / 9.0f));
          cum[k] += m ? 1.0f : 0.0f;
          cumx[k] += m ? v : 0.0f;
        }
      }
      const int d = lane + 64 * jc;  // dword index within row (0..255)
      lrow[(((d >> 2) ^ sw) << 2) | (d & 3)] = pk;
    }
#pragma unroll
    for (int off = 32; off > 0; off >>= 1) {
      totx += __shfl_xor(totx, off);
#pragma unroll
      for (int s = 0; s < 8; ++s) {
        cum[s] += __shfl_xor(cum[s], off);
        cumx[s] += __shfl_xor(cumx[s], off);
      }
    }
    if (lane == 0) {
      seg_lds[rl][0] = totx - cumx[0];
      seg_lds[rl][12] = 1024.f - cum[0];
#pragma unroll
      for (int s = 1; s < 8; ++s) {
        seg_lds[rl][s] = cumx[s - 1] - cumx[s];
        seg_lds[rl][12 + s] = cum[s - 1] - cum[s];
      }
      seg_lds[rl][8] = cumx[7];
      seg_lds[rl][20] = cum[7];
    }
  }
  __syncthreads();

  // ---- Phase 2: GEMM, B direct from L2 (coalesced tiled layout) --------
  const int nb = w * 64;
  floatx16 acc[2] = {};
  const unsigned char* aRow = lA + l31 * 1024;
  const int asw = l31 & 7;
  // base for this wave's 2 col-groups; per (kc, ni): + kc*65536 + ni*2048
  const unsigned char* bBase = Wb8 + (w * 2) * 2048 + lane * 16;

#define LOAD_A(ko, AF)                                                         \
  {                                                                            \
    const int c0 = ((ko) >> 4) + lh * 2;                                       \
    intx4 lo = *(const intx4*)(aRow + ((c0 ^ asw) << 4));                      \
    intx4 hi = *(const intx4*)(aRow + (((c0 + 1) ^ asw) << 4));                \
    AF[0] = lo[0]; AF[1] = lo[1]; AF[2] = lo[2]; AF[3] = lo[3];                \
    AF[4] = hi[0]; AF[5] = hi[1]; AF[6] = hi[2]; AF[7] = hi[3];                \
  }
#define LOAD_B(kc, ni, BF)                                                     \
  {                                                                            \
    const unsigned char* bp = bBase + (kc) * 65536 + (ni) * 2048;              \
    intx4 lo = *(const intx4*)bp;                                              \
    intx4 hi = *(const intx4*)(bp + 1024);                                     \
    BF[0] = lo[0]; BF[1] = lo[1]; BF[2] = lo[2]; BF[3] = lo[3];                \
    BF[4] = hi[0]; BF[5] = hi[1]; BF[6] = hi[2]; BF[7] = hi[3];                \
  }

  const int rot = (blockIdx.x & 7) * 2;  // per-block K-sweep rotation (even)
  for (int kt0 = 0; kt0 < 16; kt0 += 2) {  // pair-unrolled: loads lead MFMAs
    const int kt = (kt0 + rot) & 15;       // kt even -> kt+1 = kt|1, no wrap
    intx8 a0, a1, b0[2], b1[2];
    LOAD_A(kt * 64, a0);
    LOAD_A(kt * 64 + 64, a1);
#pragma unroll
    for (int ni = 0; ni < 2; ++ni) LOAD_B(kt, ni, b0[ni]);
#pragma unroll
    for (int ni = 0; ni < 2; ++ni) LOAD_B(kt + 1, ni, b1[ni]);
    __builtin_amdgcn_s_setprio(1);
#pragma unroll
    for (int ni = 0; ni < 2; ++ni)
      acc[ni] = __builtin_amdgcn_mfma_scale_f32_32x32x64_f8f6f4(
          a0, b0[ni], acc[ni], 0, 0, 0, 0x7D7D7D7Du /*A 2^-2*/, 0,
          0x7B7B7B7Bu /*B 2^-4*/);
#pragma unroll
    for (int ni = 0; ni < 2; ++ni)
      acc[ni] = __builtin_amdgcn_mfma_scale_f32_32x32x64_f8f6f4(
          a1, b1[ni], acc[ni], 0, 0, 0, 0x7D7D7D7Du, 0, 0x7B7B7B7Bu);
    __builtin_amdgcn_s_setprio(0);
  }

  // ---- Phase 3: bias + lin + LayerNorm + PReLU -------------------------
  // C/D 32x32 layout: col = lane&31, row = (rg&3) + 8*(rg>>2) + 4*(lane>>5)
  float bb[2], cs[2][9], ci[2][9];
#pragma unroll
  for (int ni = 0; ni < 2; ++ni) {
    const int c = nb + ni * 32 + l31;
    bb[ni] = biases[c];
#pragma unroll
    for (int s = 0; s < 9; ++s) {
      cs[ni][s] = slt[s * N_OUT + c];
      ci[ni][s] = ict[s * N_OUT + c];
    }
  }

#pragma unroll
  for (int rg = 0; rg < 16; ++rg) {
    const int rl = (rg & 3) + 8 * (rg >> 2) + 4 * lh;
    float sx[9], sc[9];
#pragma unroll
    for (int s = 0; s < 9; ++s) {
      sx[s] = seg_lds[rl][s];       // broadcast reads (same addr per half)
      sc[s] = seg_lds[rl][12 + s];
    }
    float ssum = 0.f, qsum = 0.f;
#pragma unroll
    for (int ni = 0; ni < 2; ++ni) {
      float y = acc[ni][rg] + bb[ni];
#pragma unroll
      for (int s = 0; s < 9; ++s) y += sx[s] * cs[ni][s] + sc[s] * ci[ni][s];
      acc[ni][rg] = y;  // keep y in-register until mu/rstd known
      ssum += y;
      qsum += y * y;
    }
#pragma unroll
    for (int off = 16; off > 0; off >>= 1) {  // stays within 32-lane half
      ssum += __shfl_xor(ssum, off);
      qsum += __shfl_xor(qsum, off);
    }
    if (l31 == 0) red[w][rl] = make_float2(ssum, qsum);  // lanes 0 and 32
  }
  __syncthreads();
  if (t < 32) {
    float s = 0.f, q = 0.f;
#pragma unroll
    for (int wv = 0; wv < 16; ++wv) {
      float2 p = red[wv][t];
      s += p.x;
      q += p.y;
    }
    const float mu = s * (1.0f / 1024.0f);
    const float rstd = rsqrtf(q * (1.0f / 1024.0f) - mu * mu + 1e-5f);
    rowstat[t] = make_float2(mu, rstd);
  }
  const float pw = prelu_w[0];
  __syncthreads();
#pragma unroll
  for (int rg = 0; rg < 16; ++rg) {
    const int rl = (rg & 3) + 8 * (rg >> 2) + 4 * lh;
    const float2 ms = rowstat[rl];
    float* orow = out + (r0 + rl) * N_OUT;
#pragma unroll
    for (int ni = 0; ni < 2; ++ni) {
      float z = (acc[ni][rg] - ms.x) * ms.y;
      z = z >= 0.f ? z : pw * z;
      __builtin_nontemporal_store(z, &orow[nb + ni * 32 + l31]);
    }
  }
}

extern "C" void kernel_launch(void* const* d_in, const int* in_sizes, int n_in,
                              void* d_out, int out_size, void* d_ws, size_t ws_size,
                              hipStream_t stream) {
  const float* x = (const float*)d_in[0];
  const float* W = (const float*)d_in[1];
  const float* biases = (const float*)d_in[2];
  const float* slopes = (const float*)d_in[3];
  const float* icpts = (const float*)d_in[4];
  const float* prelu_w = (const float*)d_in[5];
  float* out = (float*)d_out;

  char* ws = (char*)d_ws;
  unsigned char* Wb8 = (unsigned char*)ws;               // 1 MB fp8 16*W (tiled)
  float* slt = (float*)(ws + (2u << 20));                // 9*1024 fp32
  float* ict = (float*)(ws + (2u << 20) + (64u << 10));  // 9*1024 fp32

  prep_w<<<N_OUT + 64, 256, 0, stream>>>(W, Wb8, slopes, icpts, slt, ict);
  fused<<<BATCHN / 32, 1024, 0, stream>>>(x, Wb8, biases, slt, ict, prelu_w, out);
}

// Round 6
// 162.709 us; speedup vs baseline: 1.0216x; 1.0216x over previous
//
#include <hip/hip_runtime.h>
#include <hip/hip_fp8.h>

#define N_IN 1024
#define N_OUT 1024
#define BATCHN 8192

typedef __attribute__((ext_vector_type(4))) int intx4;
typedef __attribute__((ext_vector_type(8))) int intx8;
typedef __attribute__((ext_vector_type(16))) float floatx16;

// HW packed fp8 e4m3 (OCP on gfx950) convert: (a,b) -> 2 bytes, RNE+sat.
__device__ __forceinline__ unsigned int pk4_e4m3(float a, float b, float c,
                                                 float d) {
  int w = __builtin_amdgcn_cvt_pk_fp8_f32(a, b, 0, false);   // bytes 0,1
  w = __builtin_amdgcn_cvt_pk_fp8_f32(c, d, w, true);        // bytes 2,3
  return (unsigned int)w;
}
// gelu ~= v * sigmoid(1.702 v) = v * rcp(1 + exp2(-2.4554 v)).
// Max abs err ~0.02 — below the fp8 e4m3 quantization noise of the GEMM path.
__device__ __forceinline__ float gelu_fast(float v) {
  float e = __builtin_amdgcn_exp2f(-2.4554443f * v);
  return v * __builtin_amdgcn_rcpf(1.0f + e);
}

// ---------------------------------------------------------------------------
// Kernel 1: tiny prep.
// blocks [0,1024): W rows -> fp8 e4m3 (x16 scale), written in MFMA-native
//   tiled layout so GEMM B-fragment loads are fully coalesced:
//   for K64-chunk kc and 32-col group g, a 2 KB block holds
//     [sec(0: k bytes lh*32+[0,16), 1: +[16,32))][lane = lh*32 + (col&31)][16B]
//   GEMM reads it as  base + lane*16  (lo)  and  base + 1024 + lane*16  (hi).
// blocks [1024,1088): slopes/intercepts [:,0,:] gather-transpose (s-major).
// ---------------------------------------------------------------------------
__global__ __launch_bounds__(256) void prep_w(const float* __restrict__ W,
                                              unsigned char* __restrict__ Wb8,
                                              const float* __restrict__ slopes,
                                              const float* __restrict__ icpts,
                                              float* __restrict__ slt,
                                              float* __restrict__ ict) {
  const int b = blockIdx.x, t = threadIdx.x;
  if (b < N_OUT) {
    const int o = b;                      // W row == GEMM col
    float4 v = ((const float4*)(W + o * N_IN))[t];  // k bytes 4t..4t+3
    unsigned int pk =
        pk4_e4m3(v.x * 16.0f, v.y * 16.0f, v.z * 16.0f, v.w * 16.0f);
    const int kc = t >> 4;                // K64 chunk
    const int lh = (t >> 3) & 1;          // k-half within K64
    const int sec = (t >> 2) & 1;         // lo/hi 16B segment
    const int off = (t & 3) * 4;          // dword within 16B segment
    const int lane = lh * 32 + (o & 31);
    *(unsigned int*)(Wb8 + kc * 65536 + (o >> 5) * 2048 + sec * 1024 +
                     lane * 16 + off) = pk;
  } else {
    const int gb = b - N_OUT;  // 0..63
    const int o = gb * 16 + (t >> 4);
    const int s = t & 15;
    if (s < 9) {
      slt[s * N_OUT + o] = slopes[(long)o * 9216 + s];  // slopes[o][0][s]
      ict[s * N_OUT + o] = icpts[(long)o * 9216 + s];
    }
  }
}

// ---------------------------------------------------------------------------
// Kernel 2: fully fused. 256 blocks x 1024 threads (16 waves), 1 block/CU
// at 4 waves/SIMD. Block owns 32 rows x all 1024 cols.
//   Phase 1: wave w stages rows 2w..2w+1: gelu(x)*4 -> fp8 in LDS via HW
//            v_cvt_pk_fp8_f32 (16B-chunk XOR swizzle) + per-row segment
//            stats into LDS as (sx,sc) float2 pairs.
//   Phase 2: MX-fp8 GEMM. Wave w computes cols [64w,64w+64): A frags from
//            LDS, B frags direct from L2 in the MFMA-native tiled layout.
//            K-sweep start is rotated by CU-WITHIN-XCD index (blockIdx>>3),
//            so the 32 blocks sharing one XCD L2 hit 8 different regions
//            instead of convoying on the same lines. No K-loop barriers.
//   Phase 3: + bias + rank-18 lin term, full-row LayerNorm via shfl +
//            cross-wave LDS partials, PReLU, nontemporal f32 stores.
// ---------------------------------------------------------------------------
__global__ __launch_bounds__(1024) void fused(const float* __restrict__ x,
                                              const unsigned char* __restrict__ Wb8,
                                              const float* __restrict__ biases,
                                              const float* __restrict__ slt,
                                              const float* __restrict__ ict,
                                              const float* __restrict__ prelu_w,
                                              float* __restrict__ out) {
  __shared__ unsigned char lA[32 * 1024];   // 32 KB fp8 A tile (swizzled)
  __shared__ float2 seg2[32][12];           // (sx,sc) pairs, s in [0,9)
  __shared__ float2 red[16][32];            // per-wave (sum, sumsq) partials
  __shared__ float2 rowstat[32];            // (mu, rstd)

  const int t = threadIdx.x;
  const int lane = t & 63, w = t >> 6;      // 16 waves
  const int l31 = lane & 31, lh = lane >> 5;
  const int r0 = blockIdx.x * 32;

  // ---- Phase 1: stage A + segment stats (2 rows per wave) --------------
  for (int jr = 0; jr < 2; ++jr) {
    const int rl = 2 * w + jr;  // local row 0..31
    const float* xr = x + (r0 + rl) * N_IN;
    unsigned int* lrow = (unsigned int*)(lA + rl * 1024);
    const int sw = rl & 7;
    float cum[8], cumx[8], totx = 0.f;
#pragma unroll
    for (int s = 0; s < 8; ++s) { cum[s] = 0.f; cumx[s] = 0.f; }
#pragma unroll
    for (int jc = 0; jc < 4; ++jc) {
      float4 v4 = ((const float4*)xr)[lane + 64 * jc];
      float vs[4] = {v4.x, v4.y, v4.z, v4.w};
      float gs[4];
#pragma unroll
      for (int e = 0; e < 4; ++e) {
        float v = vs[e];
        gs[e] = gelu_fast(v) * 4.0f;  // x4 scale, undone by MX scale operand
        totx += v;
#pragma unroll
        for (int k = 0; k < 8; ++k) {
          bool m = v >= (-1.0f + (float)(k + 1) * (2.0f / 9.0f));
          cum[k] += m ? 1.0f : 0.0f;
          cumx[k] += m ? v : 0.0f;
        }
      }
      const unsigned int pk = pk4_e4m3(gs[0], gs[1], gs[2], gs[3]);
      const int d = lane + 64 * jc;  // dword index within row (0..255)
      lrow[(((d >> 2) ^ sw) << 2) | (d & 3)] = pk;
    }
#pragma unroll
    for (int off = 32; off > 0; off >>= 1) {
      totx += __shfl_xor(totx, off);
#pragma unroll
      for (int s = 0; s < 8; ++s) {
        cum[s] += __shfl_xor(cum[s], off);
        cumx[s] += __shfl_xor(cumx[s], off);
      }
    }
    if (lane == 0) {
      seg2[rl][0] = make_float2(totx - cumx[0], 1024.f - cum[0]);
#pragma unroll
      for (int s = 1; s < 8; ++s)
        seg2[rl][s] = make_float2(cumx[s - 1] - cumx[s], cum[s - 1] - cum[s]);
      seg2[rl][8] = make_float2(cumx[7], cum[7]);
    }
  }
  __syncthreads();

  // ---- Phase 2: GEMM, B direct from L2 (coalesced tiled layout) --------
  const int nb = w * 64;
  floatx16 acc[2] = {};
  const unsigned char* aRow = lA + l31 * 1024;
  const int asw = l31 & 7;
  // base for this wave's 2 col-groups; per (kc, ni): + kc*65536 + ni*2048
  const unsigned char* bBase = Wb8 + (w * 2) * 2048 + lane * 16;

#define LOAD_A(ko, AF)                                                         \
  {                                                                            \
    const int c0 = ((ko) >> 4) + lh * 2;                                       \
    intx4 lo = *(const intx4*)(aRow + ((c0 ^ asw) << 4));                      \
    intx4 hi = *(const intx4*)(aRow + (((c0 + 1) ^ asw) << 4));                \
    AF[0] = lo[0]; AF[1] = lo[1]; AF[2] = lo[2]; AF[3] = lo[3];                \
    AF[4] = hi[0]; AF[5] = hi[1]; AF[6] = hi[2]; AF[7] = hi[3];                \
  }
#define LOAD_B(kc, ni, BF)                                                     \
  {                                                                            \
    const unsigned char* bp = bBase + (kc) * 65536 + (ni) * 2048;              \
    intx4 lo = *(const intx4*)bp;                                              \
    intx4 hi = *(const intx4*)(bp + 1024);                                     \
    BF[0] = lo[0]; BF[1] = lo[1]; BF[2] = lo[2]; BF[3] = lo[3];                \
    BF[4] = hi[0]; BF[5] = hi[1]; BF[6] = hi[2]; BF[7] = hi[3];                \
  }

  // Rotate K sweep by CU-within-XCD (blocks land round-robin on XCDs, so
  // blockIdx>>3 indexes CUs sharing an L2). Even rotation keeps kt+1 = kt|1.
  const int rot = ((blockIdx.x >> 3) & 7) * 2;
  for (int kt0 = 0; kt0 < 16; kt0 += 2) {  // pair-unrolled: loads lead MFMAs
    const int kt = (kt0 + rot) & 15;
    intx8 a0, a1, b0[2], b1[2];
    LOAD_A(kt * 64, a0);
    LOAD_A(kt * 64 + 64, a1);
#pragma unroll
    for (int ni = 0; ni < 2; ++ni) LOAD_B(kt, ni, b0[ni]);
#pragma unroll
    for (int ni = 0; ni < 2; ++ni) LOAD_B(kt + 1, ni, b1[ni]);
    __builtin_amdgcn_s_setprio(1);
#pragma unroll
    for (int ni = 0; ni < 2; ++ni)
      acc[ni] = __builtin_amdgcn_mfma_scale_f32_32x32x64_f8f6f4(
          a0, b0[ni], acc[ni], 0, 0, 0, 0x7D7D7D7Du /*A 2^-2*/, 0,
          0x7B7B7B7Bu /*B 2^-4*/);
#pragma unroll
    for (int ni = 0; ni < 2; ++ni)
      acc[ni] = __builtin_amdgcn_mfma_scale_f32_32x32x64_f8f6f4(
          a1, b1[ni], acc[ni], 0, 0, 0, 0x7D7D7D7Du, 0, 0x7B7B7B7Bu);
    __builtin_amdgcn_s_setprio(0);
  }

  // ---- Phase 3: bias + lin + LayerNorm + PReLU -------------------------
  // C/D 32x32 layout: col = lane&31, row = (rg&3) + 8*(rg>>2) + 4*(lane>>5)
  float bb[2], cs[2][9], ci[2][9];
#pragma unroll
  for (int ni = 0; ni < 2; ++ni) {
    const int c = nb + ni * 32 + l31;
    bb[ni] = biases[c];
#pragma unroll
    for (int s = 0; s < 9; ++s) {
      cs[ni][s] = slt[s * N_OUT + c];
      ci[ni][s] = ict[s * N_OUT + c];
    }
  }

#pragma unroll
  for (int rg = 0; rg < 16; ++rg) {
    const int rl = (rg & 3) + 8 * (rg >> 2) + 4 * lh;
    float2 sp[9];
#pragma unroll
    for (int s = 0; s < 9; ++s) sp[s] = seg2[rl][s];  // b64 broadcast reads
    float ssum = 0.f, qsum = 0.f;
#pragma unroll
    for (int ni = 0; ni < 2; ++ni) {
      float y = acc[ni][rg] + bb[ni];
#pragma unroll
      for (int s = 0; s < 9; ++s) y += sp[s].x * cs[ni][s] + sp[s].y * ci[ni][s];
      acc[ni][rg] = y;  // keep y in-register until mu/rstd known
      ssum += y;
      qsum += y * y;
    }
#pragma unroll
    for (int off = 16; off > 0; off >>= 1) {  // stays within 32-lane half
      ssum += __shfl_xor(ssum, off);
      qsum += __shfl_xor(qsum, off);
    }
    if (l31 == 0) red[w][rl] = make_float2(ssum, qsum);  // lanes 0 and 32
  }
  __syncthreads();
  if (t < 32) {
    float s = 0.f, q = 0.f;
#pragma unroll
    for (int wv = 0; wv < 16; ++wv) {
      float2 p = red[wv][t];
      s += p.x;
      q += p.y;
    }
    const float mu = s * (1.0f / 1024.0f);
    const float rstd = rsqrtf(q * (1.0f / 1024.0f) - mu * mu + 1e-5f);
    rowstat[t] = make_float2(mu, rstd);
  }
  const float pw = prelu_w[0];
  __syncthreads();
#pragma unroll
  for (int rg = 0; rg < 16; ++rg) {
    const int rl = (rg & 3) + 8 * (rg >> 2) + 4 * lh;
    const float2 ms = rowstat[rl];
    float* orow = out + (r0 + rl) * N_OUT;
#pragma unroll
    for (int ni = 0; ni < 2; ++ni) {
      float z = (acc[ni][rg] - ms.x) * ms.y;
      z = z >= 0.f ? z : pw * z;
      __builtin_nontemporal_store(z, &orow[nb + ni * 32 + l31]);
    }
  }
}

extern "C" void kernel_launch(void* const* d_in, const int* in_sizes, int n_in,
                              void* d_out, int out_size, void* d_ws, size_t ws_size,
                              hipStream_t stream) {
  const float* x = (const float*)d_in[0];
  const float* W = (const float*)d_in[1];
  const float* biases = (const float*)d_in[2];
  const float* slopes = (const float*)d_in[3];
  const float* icpts = (const float*)d_in[4];
  const float* prelu_w = (const float*)d_in[5];
  float* out = (float*)d_out;

  char* ws = (char*)d_ws;
  unsigned char* Wb8 = (unsigned char*)ws;               // 1 MB fp8 16*W (tiled)
  float* slt = (float*)(ws + (2u << 20));                // 9*1024 fp32
  float* ict = (float*)(ws + (2u << 20) + (64u << 10));  // 9*1024 fp32

  prep_w<<<N_OUT + 64, 256, 0, stream>>>(W, Wb8, slopes, icpts, slt, ict);
  fused<<<BATCHN / 32, 1024, 0, stream>>>(x, Wb8, biases, slt, ict, prelu_w, out);
}